// Round 9
// baseline (455.604 us; speedup 1.0000x reference)
//
#include <hip/hip_runtime.h>
#include <math.h>

// ---------------- problem constants ----------------
#define SEQ_LEN 8
#define IN_DIM 2048
#define OUT_DIM 1152
#define NTUP 56
#define NSUP 25
#define NQ 200
#define WAY 5
#define SFRAMES 200
#define NFRAMES 1800
#define SROWS 1400
#define QROWS 11200
#define AT_STRIDE 1440   // bf16 scores/G1 row stride: 5 classes * 288
#define KC 288           // per-class padded K (280 valid + 8 zeros)
#define ALD 296          // attn LDS row stride (shorts)

typedef __attribute__((ext_vector_type(8))) short short8;
typedef __attribute__((ext_vector_type(4))) float f32x4;

__device__ __constant__ int TUP[NTUP][3] = {
{0,1,2},{0,1,3},{0,1,4},{0,1,5},{0,1,6},{0,1,7},
{0,2,3},{0,2,4},{0,2,5},{0,2,6},{0,2,7},
{0,3,4},{0,3,5},{0,3,6},{0,3,7},
{0,4,5},{0,4,6},{0,4,7},
{0,5,6},{0,5,7},
{0,6,7},
{1,2,3},{1,2,4},{1,2,5},{1,2,6},{1,2,7},
{1,3,4},{1,3,5},{1,3,6},{1,3,7},
{1,4,5},{1,4,6},{1,4,7},
{1,5,6},{1,5,7},
{1,6,7},
{2,3,4},{2,3,5},{2,3,6},{2,3,7},
{2,4,5},{2,4,6},{2,4,7},
{2,5,6},{2,5,7},
{2,6,7},
{3,4,5},{3,4,6},{3,4,7},
{3,5,6},{3,5,7},
{3,6,7},
{4,5,6},{4,5,7},
{4,6,7},
{5,6,7}};

// ---------------- bf16 helpers ----------------
__device__ __forceinline__ unsigned short f2bf(float x) {
  union { float f; unsigned int u; } v; v.f = x;
  unsigned int r = v.u + 0x7fffu + ((v.u >> 16) & 1u);
  return (unsigned short)(r >> 16);
}
__device__ __forceinline__ float bf2f(unsigned short s) {
  union { float f; unsigned int u; } v; v.u = ((unsigned int)s) << 16;
  return v.f;
}

// async 16B global -> LDS
__device__ __forceinline__ void gll16(const void* g, void* l) {
  __builtin_amdgcn_global_load_lds(
      (const __attribute__((address_space(1))) unsigned int*)g,
      (__attribute__((address_space(3))) unsigned int*)l, 16, 0, 0);
}

// ---------------- workspace byte offsets ----------------
#define APB_OFF   0UL                     // bf16 [1800][2048]
#define WT_OFF    7372800UL               // bf16 [6912][2048]
#define PB_OFF    35684352UL              // bf16 [1800][6912]
#define QKB_OFF   60567552UL              // bf16 [11200][1152]
#define SKB_OFF   86372352UL              // bf16 [1400][1152] class-sorted
#define QVB_OFF   89597952UL              // bf16 [11200][1152]
#define SVB_OFF   115402752UL             // bf16 [1400][1152] class-sorted
#define G2_OFF    118628352UL             // bf16 [5][288][288] Gram
#define SCB_OFF   119457792UL             // bf16 [11200][1440] class-padded
#define G1B_OFF   151713792UL             // bf16 [11200][1440] class-padded
#define QNORM_OFF 183969792UL             // f32  [11200]
#define RANK_OFF  184014592UL             // i32  [25]

// ---------------- k_pre: fused (X+PE)->bf16, weight transpose, rank, out-zero ----------------
__global__ __launch_bounds__(256) void k_pre(const float* __restrict__ S,
                                             const float* __restrict__ Q,
                                             const float* __restrict__ Wk,
                                             const float* __restrict__ Wv,
                                             const int* __restrict__ labels,
                                             unsigned short* __restrict__ APb,
                                             unsigned short* __restrict__ WT,
                                             int* __restrict__ rank,
                                             float* __restrict__ outz) {
  __shared__ float t[32][33];
  int b = blockIdx.x, tid = threadIdx.x;
  if (b < NFRAMES) {
    int frame = b;
    int e8 = tid * 8;
    int pos = frame & 7;
    const float c0 = -logf(10000.0f) / (float)IN_DIM;
    float pe[8];
#pragma unroll
    for (int p = 0; p < 4; ++p) {
      float dt = expf((float)(e8 + 2 * p) * c0);
      float arg = (float)pos * dt;
      pe[2 * p] = sinf(arg) * 0.1f;
      pe[2 * p + 1] = cosf(arg) * 0.1f;
    }
    const float* src = (frame < SFRAMES) ? (S + (size_t)frame * IN_DIM + e8)
                                         : (Q + (size_t)(frame - SFRAMES) * IN_DIM + e8);
    float4 x0 = ((const float4*)src)[0], x1 = ((const float4*)src)[1];
    short8 o;
    o[0] = (short)f2bf(x0.x + pe[0]); o[1] = (short)f2bf(x0.y + pe[1]);
    o[2] = (short)f2bf(x0.z + pe[2]); o[3] = (short)f2bf(x0.w + pe[3]);
    o[4] = (short)f2bf(x1.x + pe[4]); o[5] = (short)f2bf(x1.y + pe[5]);
    o[6] = (short)f2bf(x1.z + pe[6]); o[7] = (short)f2bf(x1.w + pe[7]);
    *(short8*)(APb + (size_t)frame * IN_DIM + e8) = o;
  } else if (b < NFRAMES + 13824) {
    int z = b - NFRAMES;                  // 64 k-tiles x 36 d-tiles x 6 (w,j)
    int bz = z / (64 * 36); int rem = z % (64 * 36);
    int by = rem / 64, bx = rem % 64;
    int w = bz / 3, j = bz % 3;
    const float* W = w ? Wv : Wk;
    int k0 = bx * 32, d0 = by * 32;
    int tx = tid & 31, ty = tid >> 5;
#pragma unroll
    for (int i = 0; i < 4; ++i) {
      int k = k0 + ty + i * 8;
      t[ty + i * 8][tx] = W[(size_t)(j * IN_DIM + k) * OUT_DIM + d0 + tx];
    }
    __syncthreads();
    int colbase = w * 3456 + j * 1152 + d0;
#pragma unroll
    for (int i = 0; i < 4; ++i) {
      int d = ty + i * 8;
      WT[(size_t)(colbase + d) * IN_DIM + k0 + tx] = f2bf(t[tx][d]);
    }
  } else {
    for (int i = tid; i < NQ * WAY; i += 256) outz[i] = 0.f;
    if (tid == 0) {
      for (int s = 0; s < NSUP; ++s) {
        int r = 0;
        for (int s2 = 0; s2 < NSUP; ++s2)
          r += (labels[s2] < labels[s]) || (labels[s2] == labels[s] && s2 < s);
        rank[s] = r;
      }
    }
  }
}

// ---------------- MFMA GEMM core (m97 structure) ----------------
__device__ __forceinline__ void mfma_core(const short* __restrict__ A, int lda, int maxA,
                                          const short* __restrict__ B, int ldb, int maxB,
                                          int K, short* lds, f32x4 (&acc)[4][4]) {
  int tid = threadIdx.x;
  int lane = tid & 63, wave = tid >> 6;
  int wm = wave & 1, wn = wave >> 1;
  int col = lane & 15, quad = lane >> 4;
  short* As = lds;           // [128][32]
  short* Bs = lds + 4096;    // [128][32]
  int s0 = tid, s1 = tid + 256;
  int r0 = s0 >> 2, r1 = s1 >> 2;
  int o0 = (s0 & 3) * 8, o1 = (s1 & 3) * 8;
  const short* a0p = A + (size_t)min(r0, maxA) * lda + o0;
  const short* a1p = A + (size_t)min(r1, maxA) * lda + o1;
  const short* b0p = B + (size_t)min(r0, maxB) * ldb + o0;
  const short* b1p = B + (size_t)min(r1, maxB) * ldb + o1;
  short* la0 = As + s0 * 8; short* la1 = As + s1 * 8;
  short* lb0 = Bs + s0 * 8; short* lb1 = Bs + s1 * 8;

  for (int k0 = 0; k0 < K; k0 += 32) {
    gll16(a0p + k0, la0);
    gll16(a1p + k0, la1);
    gll16(b0p + k0, lb0);
    gll16(b1p + k0, lb1);
    __syncthreads();
    short8 af[4], bf[4];
#pragma unroll
    for (int i = 0; i < 4; ++i)
      af[i] = *(const short8*)(As + (wm * 64 + i * 16 + col) * 32 + quad * 8);
#pragma unroll
    for (int j = 0; j < 4; ++j)
      bf[j] = *(const short8*)(Bs + (wn * 64 + j * 16 + col) * 32 + quad * 8);
#pragma unroll
    for (int i = 0; i < 4; ++i)
#pragma unroll
      for (int j = 0; j < 4; ++j)
        acc[i][j] = __builtin_amdgcn_mfma_f32_16x16x32_bf16(af[i], bf[j], acc[i][j], 0, 0, 0);
    __syncthreads();
  }
}

// ---------------- GEMM1: Pb[1800][6912] = APb @ WT^T ----------------
__global__ __launch_bounds__(256) void k_gemm1(const unsigned short* __restrict__ APb,
                                               const unsigned short* __restrict__ WT,
                                               unsigned short* __restrict__ Pb) {
  __shared__ short lds[8192];
  int row0 = blockIdx.y * 128, col0 = blockIdx.x * 128;
  f32x4 acc[4][4];
#pragma unroll
  for (int i = 0; i < 4; ++i)
#pragma unroll
    for (int j = 0; j < 4; ++j) acc[i][j] = (f32x4)(0.f);
  mfma_core((const short*)APb + (size_t)row0 * IN_DIM, IN_DIM, min(127, NFRAMES - 1 - row0),
            (const short*)WT + (size_t)col0 * IN_DIM, IN_DIM, 127,
            IN_DIM, lds, acc);
  int lane = threadIdx.x & 63, wave = threadIdx.x >> 6;
  int wm = wave & 1, wn = wave >> 1, col = lane & 15, quad = lane >> 4;
#pragma unroll
  for (int i = 0; i < 4; ++i)
#pragma unroll
    for (int r = 0; r < 4; ++r) {
      int gr = row0 + wm * 64 + i * 16 + quad * 4 + r;
      if (gr >= NFRAMES) continue;
#pragma unroll
      for (int j = 0; j < 4; ++j)
        Pb[(size_t)gr * 6912 + col0 + wn * 64 + j * 16 + col] = f2bf(acc[i][j][r]);
    }
}

// ---------------- combine (clip-LDS): one block per (clip, k/v) ----------------
__global__ __launch_bounds__(256) void k_combine(const unsigned short* __restrict__ Pb,
                                                 const float* __restrict__ bk,
                                                 const float* __restrict__ bv,
                                                 const float* __restrict__ g,
                                                 const float* __restrict__ bb,
                                                 const int* __restrict__ rank,
                                                 unsigned short* __restrict__ SKb,
                                                 unsigned short* __restrict__ QKb,
                                                 unsigned short* __restrict__ SVb,
                                                 unsigned short* __restrict__ QVb,
                                                 float* __restrict__ qnorm) {
  __shared__ short L[8 * 3456];
  int n = blockIdx.x, w = blockIdx.y;
  int tid = threadIdx.x;
  bool sup = n < NSUP;
  int fbase = sup ? n * SEQ_LEN : SFRAMES + (n - NSUP) * SEQ_LEN;
  for (int i = 0; i < 14; ++i) {
    int idx = tid + 256 * i;          // vec8 index < 3456
    if (idx < 3456) {
      int fr = idx / 432, off = (idx - fr * 432) * 8;
      *(short8*)(L + fr * 3456 + off) =
          *(const short8*)(Pb + (size_t)(fbase + fr) * 6912 + w * 3456 + off);
    }
  }
  __syncthreads();
  int wave = tid >> 6, lane = tid & 63;
  const float* bias = w ? bv : bk;
  float2 bi[9], gg[9], bbv[9];
#pragma unroll
  for (int i = 0; i < 9; ++i) {
    int p = lane + 64 * i;
    bi[i] = *(const float2*)(bias + 2 * p);
    if (w == 0) {
      gg[i] = *(const float2*)(g + 2 * p);
      bbv[i] = *(const float2*)(bb + 2 * p);
    }
  }
  int obase = sup ? rank[n] * NTUP : (n - NSUP) * NTUP;
  const unsigned int* Lu = (const unsigned int*)L;
  for (int t = wave; t < NTUP; t += 4) {
    int b0 = (TUP[t][0] * 3456) >> 1;
    int b1 = (TUP[t][1] * 3456 + 1152) >> 1;
    int b2 = (TUP[t][2] * 3456 + 2304) >> 1;
    float va[18];
    float sum = 0.f, sq = 0.f;
#pragma unroll
    for (int i = 0; i < 9; ++i) {
      int p = lane + 64 * i;
      unsigned int u0 = Lu[b0 + p], u1 = Lu[b1 + p], u2 = Lu[b2 + p];
      float a = bf2f((unsigned short)u0) + bf2f((unsigned short)u1) +
                bf2f((unsigned short)u2) + bi[i].x;
      float b = bf2f((unsigned short)(u0 >> 16)) + bf2f((unsigned short)(u1 >> 16)) +
                bf2f((unsigned short)(u2 >> 16)) + bi[i].y;
      va[2 * i] = a; va[2 * i + 1] = b;
      sum += a + b;
      sq += a * a + b * b;
    }
#pragma unroll
    for (int o = 32; o; o >>= 1) {
      sum += __shfl_xor(sum, o);
      sq += __shfl_xor(sq, o);
    }
    int orow = obase + t;
    if (w == 0) {
      float mean = sum * (1.f / OUT_DIM);
      float var = sq * (1.f / OUT_DIM) - mean * mean;
      float inv = rsqrtf(var + 1e-5f);
      unsigned short* outp = (sup ? SKb : QKb) + (size_t)orow * OUT_DIM;
#pragma unroll
      for (int i = 0; i < 9; ++i) {
        int p = lane + 64 * i;
        unsigned int lo = f2bf((va[2 * i] - mean) * inv * gg[i].x + bbv[i].x);
        unsigned int hi = f2bf((va[2 * i + 1] - mean) * inv * gg[i].y + bbv[i].y);
        *(unsigned int*)(outp + 2 * p) = lo | (hi << 16);
      }
    } else {
      unsigned short* outp = (sup ? SVb : QVb) + (size_t)orow * OUT_DIM;
#pragma unroll
      for (int i = 0; i < 9; ++i) {
        int p = lane + 64 * i;
        unsigned int lo = f2bf(va[2 * i]);
        unsigned int hi = f2bf(va[2 * i + 1]);
        *(unsigned int*)(outp + 2 * p) = lo | (hi << 16);
      }
      if (!sup && lane == 0) qnorm[orow] = sq;
    }
  }
}

// ---------------- merged: scores / G1 (XCD-swizzled, bf16 class-padded out) + Gram G2 tail ----------------
__global__ __launch_bounds__(256) void k_rowgemm(const unsigned short* __restrict__ QKb,
                                                 const unsigned short* __restrict__ SKb,
                                                 const unsigned short* __restrict__ QVb,
                                                 const unsigned short* __restrict__ SVb,
                                                 unsigned short* __restrict__ SCb,
                                                 unsigned short* __restrict__ G1b,
                                                 unsigned short* __restrict__ G2) {
  __shared__ short lds[8192];
  int L = blockIdx.x;
  f32x4 acc[4][4];
#pragma unroll
  for (int i = 0; i < 4; ++i)
#pragma unroll
    for (int j = 0; j < 4; ++j) acc[i][j] = (f32x4)(0.f);
  int lane = threadIdx.x & 63, wave = threadIdx.x >> 6;
  int wm = wave & 1, wn = wave >> 1, col = lane & 15, quad = lane >> 4;

  if (L < 1936) {
    int l = L, g1 = 0;
    if (l >= 968) { g1 = 1; l -= 968; }
    int rowSub = l & 7, t = l >> 3;
    int colIdx = t % 11, rowGroup = t / 11;
    int row0 = (rowGroup * 8 + rowSub) << 7;
    int col0 = colIdx << 7;
    const unsigned short* Am = g1 ? QVb : QKb;
    const unsigned short* Bm = g1 ? SVb : SKb;
    mfma_core((const short*)Am + (size_t)row0 * OUT_DIM, OUT_DIM, min(127, QROWS - 1 - row0),
              (const short*)Bm + (size_t)col0 * OUT_DIM, OUT_DIM, min(127, SROWS - 1 - col0),
              OUT_DIM, lds, acc);
    unsigned short* outp = g1 ? G1b : SCb;
    const float scl = g1 ? 1.0f : 0.029462782549439483f;  // 1/sqrt(1152)
#pragma unroll
    for (int i = 0; i < 4; ++i)
#pragma unroll
      for (int r = 0; r < 4; ++r) {
        int gr = row0 + wm * 64 + i * 16 + quad * 4 + r;
        if (gr >= QROWS) continue;
#pragma unroll
        for (int j = 0; j < 4; ++j) {
          int gc = col0 + wn * 64 + j * 16 + col;
          if (gc < SROWS) {
            int c = gc / 280;
            outp[(size_t)gr * AT_STRIDE + gc + c * 8] = f2bf(acc[i][j][r] * scl);
          }
        }
      }
  } else {
    int l = L - 1936;                 // 0..44: G2[c] = SV_c @ SV_c^T
    int c = l / 9, rem = l % 9;
    int i0 = (rem / 3) << 7, j0 = (rem % 3) << 7;
    const short* base = (const short*)SVb + (size_t)c * 280 * OUT_DIM;
    mfma_core(base + (size_t)i0 * OUT_DIM, OUT_DIM, min(127, 279 - i0),
              base + (size_t)j0 * OUT_DIM, OUT_DIM, min(127, 279 - j0),
              OUT_DIM, lds, acc);
    unsigned short* g2c = G2 + (size_t)c * KC * KC;
#pragma unroll
    for (int i = 0; i < 4; ++i)
#pragma unroll
      for (int r = 0; r < 4; ++r) {
        int gi = i0 + wm * 64 + i * 16 + quad * 4 + r;
        if (gi >= KC) continue;
#pragma unroll
        for (int j = 0; j < 4; ++j) {
          int gj = j0 + wn * 64 + j * 16 + col;
          if (gj < KC) g2c[(size_t)gi * KC + gj] = f2bf(acc[i][j][r]);
        }
      }
  }
}

// ---------------- k_attn: fused softmax + T2 + T3 (= e^T G2 e / S^2) + out atomics ----------------
// One block per (64-row tile, class). 11200 = 175*64 exactly (no row bounds checks).
// Phase 2 is barrier-free: each wave owns 16 rows x all 288 cols; B-fragments are
// read straight from global G2 (symmetric, L2-resident) into registers.
__global__ __launch_bounds__(256) void k_attn(const unsigned short* __restrict__ SCb,
                                              const unsigned short* __restrict__ G1b,
                                              const unsigned short* __restrict__ G2,
                                              const float* __restrict__ qnorm,
                                              float* __restrict__ out) {
  __shared__ short attn[64 * ALD];
  __shared__ float T2n[64];
  __shared__ float Sarr[64];
  __shared__ float val[64];
  int r0 = blockIdx.x * 64, c = blockIdx.y;
  int tid = threadIdx.x;

  // ---- phase 1: softmax numerators e = exp(s - M) -> LDS; S and T2 numerator ----
  int lr = tid >> 2, h = tid & 3;
  const unsigned short* ps = SCb + (size_t)(r0 + lr) * AT_STRIDE + c * KC;
  const unsigned short* pg = G1b + (size_t)(r0 + lr) * AT_STRIDE + c * KC;
  short8 sv[9];
  float mx = -INFINITY;
#pragma unroll
  for (int i = 0; i < 9; ++i) {
    int v = h * 9 + i;
    if (v < 35) {
      sv[i] = *(const short8*)(ps + v * 8);
#pragma unroll
      for (int j = 0; j < 8; ++j) mx = fmaxf(mx, bf2f((unsigned short)sv[i][j]));
    }
  }
  mx = fmaxf(mx, __shfl_xor(mx, 1));
  mx = fmaxf(mx, __shfl_xor(mx, 2));
  float sum = 0.f, t2 = 0.f;
#pragma unroll
  for (int i = 0; i < 9; ++i) {
    int v = h * 9 + i;
    if (v < 35) {
      short8 gv8 = *(const short8*)(pg + v * 8);
      short8 e8;
#pragma unroll
      for (int j = 0; j < 8; ++j) {
        float e = __expf(bf2f((unsigned short)sv[i][j]) - mx);
        sum += e;
        t2 += e * bf2f((unsigned short)gv8[j]);
        e8[j] = (short)f2bf(e);
      }
      *(short8*)(attn + lr * ALD + v * 8) = e8;
    } else {
      *(short8*)(attn + lr * ALD + v * 8) = (short8)0;   // zero class pad (v == 35)
    }
  }
  sum += __shfl_xor(sum, 1); sum += __shfl_xor(sum, 2);
  t2 += __shfl_xor(t2, 1); t2 += __shfl_xor(t2, 2);
  if (h == 0) { Sarr[lr] = sum; T2n[lr] = t2; }
  __syncthreads();

  // ---- phase 2: B2 = e @ G2 (symmetric), barrier-free, B-frags from global ----
  int lane = tid & 63, wave = tid >> 6;
  int col = lane & 15, quad = lane >> 4;
  const short* G2c = (const short*)G2 + (size_t)c * KC * KC;
  const short* arow = attn + (wave * 16 + col) * ALD;
  f32x4 acc[18];
#pragma unroll
  for (int j = 0; j < 18; ++j) acc[j] = (f32x4)(0.f);
#pragma unroll
  for (int kq = 0; kq < 9; ++kq) {
    int k0 = kq * 32;
    short8 af = *(const short8*)(arow + k0 + quad * 8);
#pragma unroll
    for (int j = 0; j < 18; ++j) {
      short8 bf = *(const short8*)(G2c + (size_t)(j * 16 + col) * KC + k0 + quad * 8);
      acc[j] = __builtin_amdgcn_mfma_f32_16x16x32_bf16(af, bf, acc[j], 0, 0, 0);
    }
  }
  // rowdot e^T B2 per owned row (rows are wave-exclusive: no atomics)
#pragma unroll
  for (int r = 0; r < 4; ++r) {
    int m = wave * 16 + quad * 4 + r;
    float s = 0.f;
#pragma unroll
    for (int j = 0; j < 18; ++j)
      s += bf2f((unsigned short)attn[m * ALD + j * 16 + col]) * acc[j][r];
    s += __shfl_xor(s, 1); s += __shfl_xor(s, 2);
    s += __shfl_xor(s, 4); s += __shfl_xor(s, 8);
    if (col == 0) {
      float S = Sarr[m], invS = 1.f / S;
      val[m] = qnorm[r0 + m] - 2.f * T2n[m] * invS + s * invS * invS;
    }
  }
  __syncthreads();

  // ---- phase 3: per-query reduce, one atomic per (query, class) ----
  if (tid < 3) {
    int q = r0 / NTUP + tid;
    int lo = max(q * NTUP, r0), hi = min(q * NTUP + NTUP, r0 + 64);
    if (lo < hi && q < NQ) {
      float s = 0.f;
      for (int r = lo; r < hi; ++r) s += val[r - r0];
      atomicAdd(&out[q * WAY + c], -s * (1.f / NTUP));
    }
  }
}

// ---------------- launch ----------------
extern "C" void kernel_launch(void* const* d_in, const int* in_sizes, int n_in,
                              void* d_out, int out_size, void* d_ws, size_t ws_size,
                              hipStream_t stream) {
  const float* support = (const float*)d_in[0];
  const int* labels = (const int*)d_in[1];
  const float* queries = (const float*)d_in[2];
  const float* Wk = (const float*)d_in[3];
  const float* bk = (const float*)d_in[4];
  const float* Wv = (const float*)d_in[5];
  const float* bv = (const float*)d_in[6];
  const float* ln_g = (const float*)d_in[7];
  const float* ln_b = (const float*)d_in[8];
  float* out = (float*)d_out;
  char* w8 = (char*)d_ws;

  unsigned short* APb = (unsigned short*)(w8 + APB_OFF);
  unsigned short* WT = (unsigned short*)(w8 + WT_OFF);
  unsigned short* Pb = (unsigned short*)(w8 + PB_OFF);
  unsigned short* QKb = (unsigned short*)(w8 + QKB_OFF);
  unsigned short* SKb = (unsigned short*)(w8 + SKB_OFF);
  unsigned short* QVb = (unsigned short*)(w8 + QVB_OFF);
  unsigned short* SVb = (unsigned short*)(w8 + SVB_OFF);
  unsigned short* G2 = (unsigned short*)(w8 + G2_OFF);
  unsigned short* SCb = (unsigned short*)(w8 + SCB_OFF);
  unsigned short* G1b = (unsigned short*)(w8 + G1B_OFF);
  float* QNORM = (float*)(w8 + QNORM_OFF);
  int* RANK = (int*)(w8 + RANK_OFF);

  k_pre<<<dim3(NFRAMES + 13824 + 1), dim3(256), 0, stream>>>(support, queries, Wk, Wv,
                                                             labels, APb, WT, RANK, out);
  k_gemm1<<<dim3(54, 15), dim3(256), 0, stream>>>(APb, WT, Pb);
  k_combine<<<dim3(225, 2), dim3(256), 0, stream>>>(Pb, bk, bv, ln_g, ln_b, RANK,
                                                    SKb, QKb, SVb, QVb, QNORM);
  k_rowgemm<<<dim3(1981), dim3(256), 0, stream>>>(QKb, SKb, QVb, SVb, SCb, G1b, G2);
  k_attn<<<dim3(175, 5), dim3(256), 0, stream>>>(SCb, G1b, G2, QNORM, out);
}

// Round 10
// 388.162 us; speedup vs baseline: 1.1737x; 1.1737x over previous
//
#include <hip/hip_runtime.h>
#include <math.h>

// ---------------- problem constants ----------------
#define SEQ_LEN 8
#define IN_DIM 2048
#define OUT_DIM 1152
#define NTUP 56
#define NSUP 25
#define NQ 200
#define WAY 5
#define SFRAMES 200
#define NFRAMES 1800
#define SROWS 1400
#define QROWS 11200
#define AT_STRIDE 1440   // bf16 scores/G1 row stride: 5 classes * 288
#define KC 288           // per-class padded K (280 valid + 8 zeros)
#define ALD 296          // attn LDS row stride (shorts)

typedef __attribute__((ext_vector_type(8))) short short8;
typedef __attribute__((ext_vector_type(4))) float f32x4;

__device__ __constant__ int TUP[NTUP][3] = {
{0,1,2},{0,1,3},{0,1,4},{0,1,5},{0,1,6},{0,1,7},
{0,2,3},{0,2,4},{0,2,5},{0,2,6},{0,2,7},
{0,3,4},{0,3,5},{0,3,6},{0,3,7},
{0,4,5},{0,4,6},{0,4,7},
{0,5,6},{0,5,7},
{0,6,7},
{1,2,3},{1,2,4},{1,2,5},{1,2,6},{1,2,7},
{1,3,4},{1,3,5},{1,3,6},{1,3,7},
{1,4,5},{1,4,6},{1,4,7},
{1,5,6},{1,5,7},
{1,6,7},
{2,3,4},{2,3,5},{2,3,6},{2,3,7},
{2,4,5},{2,4,6},{2,4,7},
{2,5,6},{2,5,7},
{2,6,7},
{3,4,5},{3,4,6},{3,4,7},
{3,5,6},{3,5,7},
{3,6,7},
{4,5,6},{4,5,7},
{4,6,7},
{5,6,7}};

// ---------------- bf16 helpers ----------------
__device__ __forceinline__ unsigned short f2bf(float x) {
  union { float f; unsigned int u; } v; v.f = x;
  unsigned int r = v.u + 0x7fffu + ((v.u >> 16) & 1u);
  return (unsigned short)(r >> 16);
}
__device__ __forceinline__ float bf2f(unsigned short s) {
  union { float f; unsigned int u; } v; v.u = ((unsigned int)s) << 16;
  return v.f;
}

// async 16B global -> LDS (dest = wave-uniform base + lane*16; tid-contiguous ok)
__device__ __forceinline__ void gll16(const void* g, void* l) {
  __builtin_amdgcn_global_load_lds(
      (const __attribute__((address_space(1))) unsigned int*)g,
      (__attribute__((address_space(3))) unsigned int*)l, 16, 0, 0);
}

// ---------------- workspace byte offsets ----------------
#define APB_OFF   0UL                     // bf16 [1800][2048]
#define WT_OFF    7372800UL               // bf16 [6912][2048]
#define PB_OFF    35684352UL              // bf16 [1800][6912]
#define QKB_OFF   60567552UL              // bf16 [11200][1152]
#define SKB_OFF   86372352UL              // bf16 [1400][1152] class-sorted
#define QVB_OFF   89597952UL              // bf16 [11200][1152]
#define SVB_OFF   115402752UL             // bf16 [1400][1152] class-sorted
#define G2_OFF    118628352UL             // bf16 [5][288][288] Gram
#define SCB_OFF   119457792UL             // bf16 [11200][1440] class-padded
#define G1B_OFF   151713792UL             // bf16 [11200][1440] class-padded
#define QNORM_OFF 183969792UL             // f32  [11200]
#define RANK_OFF  184014592UL             // i32  [25]

// ---------------- k_pre: fused (X+PE)->bf16, weight transpose, rank, out-zero ----------------
__global__ __launch_bounds__(256) void k_pre(const float* __restrict__ S,
                                             const float* __restrict__ Q,
                                             const float* __restrict__ Wk,
                                             const float* __restrict__ Wv,
                                             const int* __restrict__ labels,
                                             unsigned short* __restrict__ APb,
                                             unsigned short* __restrict__ WT,
                                             int* __restrict__ rank,
                                             float* __restrict__ outz) {
  __shared__ float t[32][33];
  int b = blockIdx.x, tid = threadIdx.x;
  if (b < NFRAMES) {
    int frame = b;
    int e8 = tid * 8;
    int pos = frame & 7;
    const float c0 = -logf(10000.0f) / (float)IN_DIM;
    float pe[8];
#pragma unroll
    for (int p = 0; p < 4; ++p) {
      float dt = expf((float)(e8 + 2 * p) * c0);
      float arg = (float)pos * dt;
      pe[2 * p] = sinf(arg) * 0.1f;
      pe[2 * p + 1] = cosf(arg) * 0.1f;
    }
    const float* src = (frame < SFRAMES) ? (S + (size_t)frame * IN_DIM + e8)
                                         : (Q + (size_t)(frame - SFRAMES) * IN_DIM + e8);
    float4 x0 = ((const float4*)src)[0], x1 = ((const float4*)src)[1];
    short8 o;
    o[0] = (short)f2bf(x0.x + pe[0]); o[1] = (short)f2bf(x0.y + pe[1]);
    o[2] = (short)f2bf(x0.z + pe[2]); o[3] = (short)f2bf(x0.w + pe[3]);
    o[4] = (short)f2bf(x1.x + pe[4]); o[5] = (short)f2bf(x1.y + pe[5]);
    o[6] = (short)f2bf(x1.z + pe[6]); o[7] = (short)f2bf(x1.w + pe[7]);
    *(short8*)(APb + (size_t)frame * IN_DIM + e8) = o;
  } else if (b < NFRAMES + 13824) {
    int z = b - NFRAMES;                  // 64 k-tiles x 36 d-tiles x 6 (w,j)
    int bz = z / (64 * 36); int rem = z % (64 * 36);
    int by = rem / 64, bx = rem % 64;
    int w = bz / 3, j = bz % 3;
    const float* W = w ? Wv : Wk;
    int k0 = bx * 32, d0 = by * 32;
    int tx = tid & 31, ty = tid >> 5;
#pragma unroll
    for (int i = 0; i < 4; ++i) {
      int k = k0 + ty + i * 8;
      t[ty + i * 8][tx] = W[(size_t)(j * IN_DIM + k) * OUT_DIM + d0 + tx];
    }
    __syncthreads();
    int colbase = w * 3456 + j * 1152 + d0;
#pragma unroll
    for (int i = 0; i < 4; ++i) {
      int d = ty + i * 8;
      WT[(size_t)(colbase + d) * IN_DIM + k0 + tx] = f2bf(t[tx][d]);
    }
  } else {
    for (int i = tid; i < NQ * WAY; i += 256) outz[i] = 0.f;
    if (tid == 0) {
      for (int s = 0; s < NSUP; ++s) {
        int r = 0;
        for (int s2 = 0; s2 < NSUP; ++s2)
          r += (labels[s2] < labels[s]) || (labels[s2] == labels[s] && s2 < s);
        rank[s] = r;
      }
    }
  }
}

// ---------------- MFMA GEMM core (m97 structure) ----------------
__device__ __forceinline__ void mfma_core(const short* __restrict__ A, int lda, int maxA,
                                          const short* __restrict__ B, int ldb, int maxB,
                                          int K, short* lds, f32x4 (&acc)[4][4]) {
  int tid = threadIdx.x;
  int lane = tid & 63, wave = tid >> 6;
  int wm = wave & 1, wn = wave >> 1;
  int col = lane & 15, quad = lane >> 4;
  short* As = lds;           // [128][32]
  short* Bs = lds + 4096;    // [128][32]
  int s0 = tid, s1 = tid + 256;
  int r0 = s0 >> 2, r1 = s1 >> 2;
  int o0 = (s0 & 3) * 8, o1 = (s1 & 3) * 8;
  const short* a0p = A + (size_t)min(r0, maxA) * lda + o0;
  const short* a1p = A + (size_t)min(r1, maxA) * lda + o1;
  const short* b0p = B + (size_t)min(r0, maxB) * ldb + o0;
  const short* b1p = B + (size_t)min(r1, maxB) * ldb + o1;
  short* la0 = As + s0 * 8; short* la1 = As + s1 * 8;
  short* lb0 = Bs + s0 * 8; short* lb1 = Bs + s1 * 8;

  for (int k0 = 0; k0 < K; k0 += 32) {
    gll16(a0p + k0, la0);
    gll16(a1p + k0, la1);
    gll16(b0p + k0, lb0);
    gll16(b1p + k0, lb1);
    __syncthreads();
    short8 af[4], bf[4];
#pragma unroll
    for (int i = 0; i < 4; ++i)
      af[i] = *(const short8*)(As + (wm * 64 + i * 16 + col) * 32 + quad * 8);
#pragma unroll
    for (int j = 0; j < 4; ++j)
      bf[j] = *(const short8*)(Bs + (wn * 64 + j * 16 + col) * 32 + quad * 8);
#pragma unroll
    for (int i = 0; i < 4; ++i)
#pragma unroll
      for (int j = 0; j < 4; ++j)
        acc[i][j] = __builtin_amdgcn_mfma_f32_16x16x32_bf16(af[i], bf[j], acc[i][j], 0, 0, 0);
    __syncthreads();
  }
}

// ---------------- GEMM1: Pb[1800][6912] = APb @ WT^T ----------------
__global__ __launch_bounds__(256) void k_gemm1(const unsigned short* __restrict__ APb,
                                               const unsigned short* __restrict__ WT,
                                               unsigned short* __restrict__ Pb) {
  __shared__ short lds[8192];
  int row0 = blockIdx.y * 128, col0 = blockIdx.x * 128;
  f32x4 acc[4][4];
#pragma unroll
  for (int i = 0; i < 4; ++i)
#pragma unroll
    for (int j = 0; j < 4; ++j) acc[i][j] = (f32x4)(0.f);
  mfma_core((const short*)APb + (size_t)row0 * IN_DIM, IN_DIM, min(127, NFRAMES - 1 - row0),
            (const short*)WT + (size_t)col0 * IN_DIM, IN_DIM, 127,
            IN_DIM, lds, acc);
  int lane = threadIdx.x & 63, wave = threadIdx.x >> 6;
  int wm = wave & 1, wn = wave >> 1, col = lane & 15, quad = lane >> 4;
#pragma unroll
  for (int i = 0; i < 4; ++i)
#pragma unroll
    for (int r = 0; r < 4; ++r) {
      int gr = row0 + wm * 64 + i * 16 + quad * 4 + r;
      if (gr >= NFRAMES) continue;
#pragma unroll
      for (int j = 0; j < 4; ++j)
        Pb[(size_t)gr * 6912 + col0 + wn * 64 + j * 16 + col] = f2bf(acc[i][j][r]);
    }
}

// ---------------- combine (clip-LDS): one block per (clip, k/v) ----------------
__global__ __launch_bounds__(256) void k_combine(const unsigned short* __restrict__ Pb,
                                                 const float* __restrict__ bk,
                                                 const float* __restrict__ bv,
                                                 const float* __restrict__ g,
                                                 const float* __restrict__ bb,
                                                 const int* __restrict__ rank,
                                                 unsigned short* __restrict__ SKb,
                                                 unsigned short* __restrict__ QKb,
                                                 unsigned short* __restrict__ SVb,
                                                 unsigned short* __restrict__ QVb,
                                                 float* __restrict__ qnorm) {
  __shared__ short L[8 * 3456];
  int n = blockIdx.x, w = blockIdx.y;
  int tid = threadIdx.x;
  bool sup = n < NSUP;
  int fbase = sup ? n * SEQ_LEN : SFRAMES + (n - NSUP) * SEQ_LEN;
  for (int i = 0; i < 14; ++i) {
    int idx = tid + 256 * i;          // vec8 index < 3456
    if (idx < 3456) {
      int fr = idx / 432, off = (idx - fr * 432) * 8;
      *(short8*)(L + fr * 3456 + off) =
          *(const short8*)(Pb + (size_t)(fbase + fr) * 6912 + w * 3456 + off);
    }
  }
  __syncthreads();
  int wave = tid >> 6, lane = tid & 63;
  const float* bias = w ? bv : bk;
  float2 bi[9], gg[9], bbv[9];
#pragma unroll
  for (int i = 0; i < 9; ++i) {
    int p = lane + 64 * i;
    bi[i] = *(const float2*)(bias + 2 * p);
    if (w == 0) {
      gg[i] = *(const float2*)(g + 2 * p);
      bbv[i] = *(const float2*)(bb + 2 * p);
    }
  }
  int obase = sup ? rank[n] * NTUP : (n - NSUP) * NTUP;
  const unsigned int* Lu = (const unsigned int*)L;
  for (int t = wave; t < NTUP; t += 4) {
    int b0 = (TUP[t][0] * 3456) >> 1;
    int b1 = (TUP[t][1] * 3456 + 1152) >> 1;
    int b2 = (TUP[t][2] * 3456 + 2304) >> 1;
    float va[18];
    float sum = 0.f, sq = 0.f;
#pragma unroll
    for (int i = 0; i < 9; ++i) {
      int p = lane + 64 * i;
      unsigned int u0 = Lu[b0 + p], u1 = Lu[b1 + p], u2 = Lu[b2 + p];
      float a = bf2f((unsigned short)u0) + bf2f((unsigned short)u1) +
                bf2f((unsigned short)u2) + bi[i].x;
      float b = bf2f((unsigned short)(u0 >> 16)) + bf2f((unsigned short)(u1 >> 16)) +
                bf2f((unsigned short)(u2 >> 16)) + bi[i].y;
      va[2 * i] = a; va[2 * i + 1] = b;
      sum += a + b;
      sq += a * a + b * b;
    }
#pragma unroll
    for (int o = 32; o; o >>= 1) {
      sum += __shfl_xor(sum, o);
      sq += __shfl_xor(sq, o);
    }
    int orow = obase + t;
    if (w == 0) {
      float mean = sum * (1.f / OUT_DIM);
      float var = sq * (1.f / OUT_DIM) - mean * mean;
      float inv = rsqrtf(var + 1e-5f);
      unsigned short* outp = (sup ? SKb : QKb) + (size_t)orow * OUT_DIM;
#pragma unroll
      for (int i = 0; i < 9; ++i) {
        int p = lane + 64 * i;
        unsigned int lo = f2bf((va[2 * i] - mean) * inv * gg[i].x + bbv[i].x);
        unsigned int hi = f2bf((va[2 * i + 1] - mean) * inv * gg[i].y + bbv[i].y);
        *(unsigned int*)(outp + 2 * p) = lo | (hi << 16);
      }
    } else {
      unsigned short* outp = (sup ? SVb : QVb) + (size_t)orow * OUT_DIM;
#pragma unroll
      for (int i = 0; i < 9; ++i) {
        int p = lane + 64 * i;
        unsigned int lo = f2bf(va[2 * i]);
        unsigned int hi = f2bf(va[2 * i + 1]);
        *(unsigned int*)(outp + 2 * p) = lo | (hi << 16);
      }
      if (!sup && lane == 0) qnorm[orow] = sq;
    }
  }
}

// ---------------- merged: scores / G1 (XCD-swizzled, bf16 class-padded out) + Gram G2 tail ----------------
__global__ __launch_bounds__(256) void k_rowgemm(const unsigned short* __restrict__ QKb,
                                                 const unsigned short* __restrict__ SKb,
                                                 const unsigned short* __restrict__ QVb,
                                                 const unsigned short* __restrict__ SVb,
                                                 unsigned short* __restrict__ SCb,
                                                 unsigned short* __restrict__ G1b,
                                                 unsigned short* __restrict__ G2) {
  __shared__ short lds[8192];
  int L = blockIdx.x;
  f32x4 acc[4][4];
#pragma unroll
  for (int i = 0; i < 4; ++i)
#pragma unroll
    for (int j = 0; j < 4; ++j) acc[i][j] = (f32x4)(0.f);
  int lane = threadIdx.x & 63, wave = threadIdx.x >> 6;
  int wm = wave & 1, wn = wave >> 1, col = lane & 15, quad = lane >> 4;

  if (L < 1936) {
    int l = L, g1 = 0;
    if (l >= 968) { g1 = 1; l -= 968; }
    int rowSub = l & 7, t = l >> 3;
    int colIdx = t % 11, rowGroup = t / 11;
    int row0 = (rowGroup * 8 + rowSub) << 7;
    int col0 = colIdx << 7;
    const unsigned short* Am = g1 ? QVb : QKb;
    const unsigned short* Bm = g1 ? SVb : SKb;
    mfma_core((const short*)Am + (size_t)row0 * OUT_DIM, OUT_DIM, min(127, QROWS - 1 - row0),
              (const short*)Bm + (size_t)col0 * OUT_DIM, OUT_DIM, min(127, SROWS - 1 - col0),
              OUT_DIM, lds, acc);
    unsigned short* outp = g1 ? G1b : SCb;
    const float scl = g1 ? 1.0f : 0.029462782549439483f;  // 1/sqrt(1152)
#pragma unroll
    for (int i = 0; i < 4; ++i)
#pragma unroll
      for (int r = 0; r < 4; ++r) {
        int gr = row0 + wm * 64 + i * 16 + quad * 4 + r;
        if (gr >= QROWS) continue;
#pragma unroll
        for (int j = 0; j < 4; ++j) {
          int gc = col0 + wn * 64 + j * 16 + col;
          if (gc < SROWS) {
            int c = gc / 280;
            outp[(size_t)gr * AT_STRIDE + gc + c * 8] = f2bf(acc[i][j][r] * scl);
          }
        }
      }
  } else {
    int l = L - 1936;                 // 0..44: G2[c] = SV_c @ SV_c^T
    int c = l / 9, rem = l % 9;
    int i0 = (rem / 3) << 7, j0 = (rem % 3) << 7;
    const short* base = (const short*)SVb + (size_t)c * 280 * OUT_DIM;
    mfma_core(base + (size_t)i0 * OUT_DIM, OUT_DIM, min(127, 279 - i0),
              base + (size_t)j0 * OUT_DIM, OUT_DIM, min(127, 279 - j0),
              OUT_DIM, lds, acc);
    unsigned short* g2c = G2 + (size_t)c * KC * KC;
#pragma unroll
    for (int i = 0; i < 4; ++i)
#pragma unroll
      for (int r = 0; r < 4; ++r) {
        int gi = i0 + wm * 64 + i * 16 + quad * 4 + r;
        if (gi >= KC) continue;
#pragma unroll
        for (int j = 0; j < 4; ++j) {
          int gj = j0 + wn * 64 + j * 16 + col;
          if (gj < KC) g2c[(size_t)gi * KC + gj] = f2bf(acc[i][j][r]);
        }
      }
  }
}

// ---------------- k_attn: fused softmax + T2 + T3 (= e^T G2 e / S^2) + out atomics ----------------
// One block per (64-row tile, class). attn (e = exp(s-M), bf16) lives in LDS.
// Phase 2: for each 64-col slab of G2, stage the slab's FULL K (64x288 = 36.9 KB)
// once via gll16, then 9 barrier-free k-steps of MFMA from LDS. 10 barriers/block
// (vs 54 in the 8KB-piece version). G2 read exactly once per block.
__global__ __launch_bounds__(256) void k_attn(const unsigned short* __restrict__ SCb,
                                              const unsigned short* __restrict__ G1b,
                                              const unsigned short* __restrict__ G2,
                                              const float* __restrict__ qnorm,
                                              float* __restrict__ out) {
  __shared__ short attn[64 * ALD];     // 37,888 B
  __shared__ short Bs[64 * KC];        // 36,864 B
  __shared__ float T2n[64];
  __shared__ float Sarr[64];
  __shared__ float rowsum[64];
  __shared__ float val[64];
  int r0 = blockIdx.x * 64, c = blockIdx.y;
  int tid = threadIdx.x;

  // ---- phase 1: softmax numerators e = exp(s - M) -> LDS; S and T2 numerator ----
  int lr = tid >> 2, h = tid & 3;
  const unsigned short* ps = SCb + (size_t)(r0 + lr) * AT_STRIDE + c * KC;
  const unsigned short* pg = G1b + (size_t)(r0 + lr) * AT_STRIDE + c * KC;
  short8 sv[9];
  float mx = -INFINITY;
#pragma unroll
  for (int i = 0; i < 9; ++i) {
    int v = h * 9 + i;
    if (v < 35) {
      sv[i] = *(const short8*)(ps + v * 8);
#pragma unroll
      for (int j = 0; j < 8; ++j) mx = fmaxf(mx, bf2f((unsigned short)sv[i][j]));
    }
  }
  mx = fmaxf(mx, __shfl_xor(mx, 1));
  mx = fmaxf(mx, __shfl_xor(mx, 2));
  float sum = 0.f, t2 = 0.f;
#pragma unroll
  for (int i = 0; i < 9; ++i) {
    int v = h * 9 + i;
    if (v < 35) {
      short8 gv8 = *(const short8*)(pg + v * 8);
      short8 e8;
#pragma unroll
      for (int j = 0; j < 8; ++j) {
        float e = __expf(bf2f((unsigned short)sv[i][j]) - mx);
        sum += e;
        t2 += e * bf2f((unsigned short)gv8[j]);
        e8[j] = (short)f2bf(e);
      }
      *(short8*)(attn + lr * ALD + v * 8) = e8;
    } else {
      *(short8*)(attn + lr * ALD + v * 8) = (short8)0;   // zero class pad (v == 35)
    }
  }
  sum += __shfl_xor(sum, 1); sum += __shfl_xor(sum, 2);
  t2 += __shfl_xor(t2, 1); t2 += __shfl_xor(t2, 2);
  if (h == 0) { Sarr[lr] = sum; T2n[lr] = t2; }
  if (tid < 64) rowsum[tid] = 0.f;
  __syncthreads();

  // ---- phase 2: B2 = e @ G2 per 64-col slab; B staged full-K once per slab ----
  int lane = tid & 63, wave = tid >> 6;
  int col = lane & 15, quad = lane >> 4;
  const short* G2c = (const short*)G2 + (size_t)c * KC * KC;
  float part[4][4] = {};
  for (int j0 = 0; j0 < KC; j0 += 64) {
    int ncols = min(64, KC - j0);            // 64,64,64,64,32
    int chunks = ncols * 36;                 // 16-B chunks: 2304 or 1152
    for (int base = 0; base < chunks; base += 256) {
      int idx = base + tid;
      if (idx < chunks) {
        int n = idx / 36, kk = idx - n * 36;
        gll16(G2c + (size_t)(j0 + n) * KC + kk * 8, Bs + idx * 8);
      }
    }
    __syncthreads();
    if (wave * 16 < ncols) {
      f32x4 acc[4];
#pragma unroll
      for (int i = 0; i < 4; ++i) acc[i] = (f32x4)(0.f);
      for (int kq = 0; kq < 9; ++kq) {
        short8 bf = *(const short8*)(Bs + (wave * 16 + col) * KC + kq * 32 + quad * 8);
#pragma unroll
        for (int i = 0; i < 4; ++i) {
          short8 af = *(const short8*)(attn + (i * 16 + col) * ALD + kq * 32 + quad * 8);
          acc[i] = __builtin_amdgcn_mfma_f32_16x16x32_bf16(af, bf, acc[i], 0, 0, 0);
        }
      }
      int gcol = j0 + wave * 16 + col;
#pragma unroll
      for (int i = 0; i < 4; ++i)
#pragma unroll
        for (int r = 0; r < 4; ++r)
          part[i][r] += bf2f((unsigned short)attn[(i * 16 + quad * 4 + r) * ALD + gcol]) *
                        acc[i][r];
    }
    __syncthreads();
  }
  // reduce rowdot across the wave's 16 cols, then across waves via LDS atomics
#pragma unroll
  for (int i = 0; i < 4; ++i)
#pragma unroll
    for (int r = 0; r < 4; ++r) {
      float s = part[i][r];
      s += __shfl_xor(s, 1); s += __shfl_xor(s, 2);
      s += __shfl_xor(s, 4); s += __shfl_xor(s, 8);
      if (col == 0) atomicAdd(&rowsum[i * 16 + quad * 4 + r], s);
    }
  __syncthreads();

  // ---- phase 3: per-row distance, per-query reduce, one atomic per (q, c) ----
  if (tid < 64) {
    float S = Sarr[tid], invS = 1.f / S;
    val[tid] = qnorm[r0 + tid] - 2.f * T2n[tid] * invS + rowsum[tid] * invS * invS;
  }
  __syncthreads();
  if (tid < 3) {
    int q = r0 / NTUP + tid;
    int lo = max(q * NTUP, r0), hi = min(q * NTUP + NTUP, r0 + 64);
    if (lo < hi && q < NQ) {
      float s = 0.f;
      for (int r = lo; r < hi; ++r) s += val[r - r0];
      atomicAdd(&out[q * WAY + c], -s * (1.f / NTUP));
    }
  }
}

// ---------------- launch ----------------
extern "C" void kernel_launch(void* const* d_in, const int* in_sizes, int n_in,
                              void* d_out, int out_size, void* d_ws, size_t ws_size,
                              hipStream_t stream) {
  const float* support = (const float*)d_in[0];
  const int* labels = (const int*)d_in[1];
  const float* queries = (const float*)d_in[2];
  const float* Wk = (const float*)d_in[3];
  const float* bk = (const float*)d_in[4];
  const float* Wv = (const float*)d_in[5];
  const float* bv = (const float*)d_in[6];
  const float* ln_g = (const float*)d_in[7];
  const float* ln_b = (const float*)d_in[8];
  float* out = (float*)d_out;
  char* w8 = (char*)d_ws;

  unsigned short* APb = (unsigned short*)(w8 + APB_OFF);
  unsigned short* WT = (unsigned short*)(w8 + WT_OFF);
  unsigned short* Pb = (unsigned short*)(w8 + PB_OFF);
  unsigned short* QKb = (unsigned short*)(w8 + QKB_OFF);
  unsigned short* SKb = (unsigned short*)(w8 + SKB_OFF);
  unsigned short* QVb = (unsigned short*)(w8 + QVB_OFF);
  unsigned short* SVb = (unsigned short*)(w8 + SVB_OFF);
  unsigned short* G2 = (unsigned short*)(w8 + G2_OFF);
  unsigned short* SCb = (unsigned short*)(w8 + SCB_OFF);
  unsigned short* G1b = (unsigned short*)(w8 + G1B_OFF);
  float* QNORM = (float*)(w8 + QNORM_OFF);
  int* RANK = (int*)(w8 + RANK_OFF);

  k_pre<<<dim3(NFRAMES + 13824 + 1), dim3(256), 0, stream>>>(support, queries, Wk, Wv,
                                                             labels, APb, WT, RANK, out);
  k_gemm1<<<dim3(54, 15), dim3(256), 0, stream>>>(APb, WT, Pb);
  k_combine<<<dim3(225, 2), dim3(256), 0, stream>>>(Pb, bk, bv, ln_g, ln_b, RANK,
                                                    SKb, QKb, SVb, QVb, QNORM);
  k_rowgemm<<<dim3(1981), dim3(256), 0, stream>>>(QKb, SKb, QVb, SVb, SCb, G1b, G2);
  k_attn<<<dim3(175, 5), dim3(256), 0, stream>>>(SCb, G1b, G2, QNORM, out);
}